// Round 3
// baseline (232.794 us; speedup 1.0000x reference)
//
#include <hip/hip_runtime.h>
#include <hip/hip_bf16.h>

// Problem constants
#define B_   4
#define T_   4096
#define C_   512
#define H_   8
#define D_   64
#define KS_  9
#define PAD_ 4
#define MTOT (B_ * T_)   // 16384

typedef __bf16 bf16_t;
typedef __bf16 bf16x8 __attribute__((ext_vector_type(8)));
typedef float  f32x4  __attribute__((ext_vector_type(4)));

// ---------------------------------------------------------------------------
// Dtype detector: sample 4096 ushorts of x. If data is bf16, ~100% have a
// bf16 exponent field in [112,143] (values in [2^-15, 2^16], true for N(0,1)).
// If data is fp32, even words are deep-mantissa noise (~12.5% sane) ->
// overall ~56%. flag = 1 means "inputs are fp32".
// ---------------------------------------------------------------------------
__global__ void detect_dtype(const unsigned short* __restrict__ xs,
                             int* __restrict__ flag) {
  __shared__ int cnt;
  if (threadIdx.x == 0) cnt = 0;
  __syncthreads();
  int sane = 0;
  for (int i = threadIdx.x; i < 4096; i += 256) {
    int e = (xs[i] >> 7) & 0xFF;
    if (e >= 112 && e <= 143) sane++;
  }
  atomicAdd(&cnt, sane);
  __syncthreads();
  if (threadIdx.x == 0) *flag = (cnt < 3300) ? 1 : 0;
}

// Convert n8*8 elements to bf16 (from fp32 if *flag, else plain bf16 copy).
__global__ void conv_mat(const void* __restrict__ src, bf16_t* __restrict__ dst,
                         int n8, const int* __restrict__ flag) {
  int i = blockIdx.x * 256 + threadIdx.x;
  if (i >= n8) return;
  bf16x8 o;
  if (*flag) {
    const float* s = (const float*)src + (size_t)i * 8;
#pragma unroll
    for (int e = 0; e < 8; ++e) o[e] = (bf16_t)s[e];
  } else {
    o = *((const bf16x8*)src + i);
  }
  *((bf16x8*)dst + i) = o;
}

// All four biases -> fp32, packed [bq | bk | bv | bo] at stride 512.
__global__ void conv_bias(const void* __restrict__ s0, const void* __restrict__ s1,
                          const void* __restrict__ s2, const void* __restrict__ s3,
                          float* __restrict__ dst, const int* __restrict__ flag) {
  int i = blockIdx.x * 256 + threadIdx.x;   // 0..2047
  int which = i >> 9, j = i & 511;
  const void* s = which == 0 ? s0 : which == 1 ? s1 : which == 2 ? s2 : s3;
  dst[i] = (*flag) ? ((const float*)s)[j] : (float)((const bf16_t*)s)[j];
}

// ---------------------------------------------------------------------------
// GEMM core: C[M,N] = A[M,K] * W[N,K]^T + bias   (K = N = 512, bf16 MFMA)
// 128x128 tile, BK=32, mfma_f32_16x16x32_bf16, register staging (m92).
// 256 threads = 4 waves 2x2; each wave 4x4 16x16 subtiles (64x64).
// f32out selects the output element type (uniform branch).
// ---------------------------------------------------------------------------
__device__ __forceinline__ void gemm_core(const bf16_t* __restrict__ A,
                                          const bf16_t* __restrict__ W,
                                          const float* __restrict__ bias,
                                          void* __restrict__ Cout, bool f32out,
                                          int m0, int n0) {
  constexpr int K = C_;
  constexpr int N = C_;
  __shared__ __align__(16) bf16_t lsA[128 * 32];
  __shared__ __align__(16) bf16_t lsB[128 * 32];

  const int tid  = threadIdx.x;
  const int lane = tid & 63;
  const int wave = tid >> 6;
  const int wm   = (wave >> 1) * 64;
  const int wn   = (wave & 1) * 64;

  const int r0 = tid >> 2;             // rows 0..63
  const int p0 = (tid & 3) << 3;
  const int r1 = r0 + 64;              // rows 64..127

  f32x4 acc[4][4] = {};

  for (int k0 = 0; k0 < K; k0 += 32) {
    bf16x8 a0 = *(const bf16x8*)(A + (size_t)(m0 + r0) * K + (k0 + p0));
    bf16x8 b0 = *(const bf16x8*)(W + (size_t)(n0 + r0) * K + (k0 + p0));
    bf16x8 a1 = *(const bf16x8*)(A + (size_t)(m0 + r1) * K + (k0 + p0));
    bf16x8 b1 = *(const bf16x8*)(W + (size_t)(n0 + r1) * K + (k0 + p0));

    __syncthreads();
    *(bf16x8*)&lsA[(size_t)tid * 8]         = a0;
    *(bf16x8*)&lsA[(size_t)(tid + 256) * 8] = a1;
    *(bf16x8*)&lsB[(size_t)tid * 8]         = b0;
    *(bf16x8*)&lsB[(size_t)(tid + 256) * 8] = b1;
    __syncthreads();

    const int kq = (lane >> 4) << 3;
    const int rr = lane & 15;
    bf16x8 af[4], bfr[4];
#pragma unroll
    for (int i = 0; i < 4; ++i) {
      af[i]  = *(const bf16x8*)&lsA[(wm + i * 16 + rr) * 32 + kq];
      bfr[i] = *(const bf16x8*)&lsB[(wn + i * 16 + rr) * 32 + kq];
    }
#pragma unroll
    for (int i = 0; i < 4; ++i)
#pragma unroll
      for (int j = 0; j < 4; ++j)
        acc[i][j] = __builtin_amdgcn_mfma_f32_16x16x32_bf16(af[i], bfr[j],
                                                            acc[i][j], 0, 0, 0);
  }

  // C/D layout: col = lane&15, row = (lane>>4)*4 + reg  [m89]
  const int cn = lane & 15;
  const int rb = (lane >> 4) << 2;
  float bvals[4];
#pragma unroll
  for (int j = 0; j < 4; ++j) bvals[j] = bias[wn + j * 16 + cn + n0];
#pragma unroll
  for (int i = 0; i < 4; ++i) {
#pragma unroll
    for (int r = 0; r < 4; ++r) {
      int gm = m0 + wm + i * 16 + rb + r;
      if (f32out) {
        float* orow = (float*)Cout + (size_t)gm * N + (n0 + wn);
#pragma unroll
        for (int j = 0; j < 4; ++j)
          orow[j * 16 + cn] = acc[i][j][r] + bvals[j];
      } else {
        bf16_t* orow = (bf16_t*)Cout + (size_t)gm * N + (n0 + wn);
#pragma unroll
        for (int j = 0; j < 4; ++j)
          orow[j * 16 + cn] = (bf16_t)(acc[i][j][r] + bvals[j]);
      }
    }
  }
}

__global__ __launch_bounds__(256, 2)
void qkv_gemm(const bf16_t* __restrict__ xb, const bf16_t* __restrict__ Wb,
              const float* __restrict__ biasf, bf16_t* __restrict__ qkv) {
  const int z = blockIdx.z;                       // 0=q 1=k 2=v
  gemm_core(xb, Wb + (size_t)z * C_ * C_, biasf + z * C_,
            qkv + (size_t)z * MTOT * C_, false,
            blockIdx.y * 128, blockIdx.x * 128);
}

// out dtype decided at runtime by flag (1 = fp32 out, 0 = bf16 out).
__global__ __launch_bounds__(256, 2)
void out_gemm(const bf16_t* __restrict__ y, const bf16_t* __restrict__ Wob,
              const float* __restrict__ biasf, void* __restrict__ out,
              const int* __restrict__ flag) {
  gemm_core(y, Wob, biasf, out, (*flag) != 0,
            blockIdx.y * 128, blockIdx.x * 128);
}

// ---------------------------------------------------------------------------
// Neighborhood attention: one thread per (b,h,t); 9 scores in registers,
// fp32 softmax. qkv layout: 3 planes of (b, t, h*64+d). Edge pad = clamp.
// ---------------------------------------------------------------------------
__global__ __launch_bounds__(256)
void attn_kernel(const bf16_t* __restrict__ qkv, bf16_t* __restrict__ y) {
  const int t = blockIdx.x * 256 + threadIdx.x;
  const int h = blockIdx.y;
  const int b = blockIdx.z;

  const bf16_t* q = qkv;
  const bf16_t* k = qkv + (size_t)MTOT * C_;
  const bf16_t* v = qkv + (size_t)2 * MTOT * C_;

  const size_t base = (size_t)b * T_ * C_ + (size_t)h * D_;
  const bf16_t* qr = q + base + (size_t)t * C_;

  int tj[KS_];
#pragma unroll
  for (int j = 0; j < KS_; ++j) {
    int tt = t - PAD_ + j;
    tj[j] = tt < 0 ? 0 : (tt >= T_ ? T_ - 1 : tt);
  }

  float s[KS_];
#pragma unroll
  for (int j = 0; j < KS_; ++j) s[j] = 0.f;

  for (int c = 0; c < D_; c += 8) {
    bf16x8 q8 = *(const bf16x8*)(qr + c);
    float qf[8];
#pragma unroll
    for (int e = 0; e < 8; ++e) qf[e] = (float)q8[e];
#pragma unroll
    for (int j = 0; j < KS_; ++j) {
      bf16x8 k8 = *(const bf16x8*)(k + base + (size_t)tj[j] * C_ + c);
      float d0 = 0.f;
#pragma unroll
      for (int e = 0; e < 8; ++e) d0 += qf[e] * (float)k8[e];
      s[j] += d0;
    }
  }

  float mx = s[0];
#pragma unroll
  for (int j = 1; j < KS_; ++j) mx = fmaxf(mx, s[j]);
  float w[KS_], sum = 0.f;
#pragma unroll
  for (int j = 0; j < KS_; ++j) {
    w[j] = __expf((s[j] - mx) * 0.125f);   // scale = 1/sqrt(64)
    sum += w[j];
  }
  const float inv = 1.f / sum;
#pragma unroll
  for (int j = 0; j < KS_; ++j) w[j] *= inv;

  bf16_t* yr = y + base + (size_t)t * C_;
  for (int c = 0; c < D_; c += 8) {
    float o[8] = {0.f, 0.f, 0.f, 0.f, 0.f, 0.f, 0.f, 0.f};
#pragma unroll
    for (int j = 0; j < KS_; ++j) {
      bf16x8 v8 = *(const bf16x8*)(v + base + (size_t)tj[j] * C_ + c);
#pragma unroll
      for (int e = 0; e < 8; ++e) o[e] += w[j] * (float)v8[e];
    }
    bf16x8 o8;
#pragma unroll
    for (int e = 0; e < 8; ++e) o8[e] = (bf16_t)o[e];
    *(bf16x8*)(yr + c) = o8;
  }
}

// ---------------------------------------------------------------------------
extern "C" void kernel_launch(void* const* d_in, const int* in_sizes, int n_in,
                              void* d_out, int out_size, void* d_ws, size_t ws_size,
                              hipStream_t stream) {
  const void* x  = d_in[0];
  const void* Wq = d_in[1]; const void* bq = d_in[2];
  const void* Wk = d_in[3]; const void* bk = d_in[4];
  const void* Wv = d_in[5]; const void* bv = d_in[6];
  const void* Wo = d_in[7]; const void* bo = d_in[8];

  // Workspace layout
  char* ws = (char*)d_ws;
  int*    flag  = (int*)ws;                                   // 4 B
  bf16_t* xb    = (bf16_t*)(ws + 256);                        // 16 MB
  bf16_t* Wb    = xb + (size_t)MTOT * C_;                     // 4 * C*C bf16 (q,k,v,o)
  float*  biasf = (float*)(Wb + (size_t)4 * C_ * C_);         // 4*512 fp32
  bf16_t* qkv   = (bf16_t*)(biasf + 4 * C_);                  // 48 MB
  bf16_t* y     = qkv + (size_t)3 * MTOT * C_;                // 16 MB

  detect_dtype<<<1, 256, 0, stream>>>((const unsigned short*)x, flag);

  const int xe8 = MTOT * C_ / 8;      // 1,048,576
  const int we8 = C_ * C_ / 8;        // 32,768
  conv_mat<<<(xe8 + 255) / 256, 256, 0, stream>>>(x, xb, xe8, flag);
  conv_mat<<<(we8 + 255) / 256, 256, 0, stream>>>(Wq, Wb + (size_t)0 * C_ * C_, we8, flag);
  conv_mat<<<(we8 + 255) / 256, 256, 0, stream>>>(Wk, Wb + (size_t)1 * C_ * C_, we8, flag);
  conv_mat<<<(we8 + 255) / 256, 256, 0, stream>>>(Wv, Wb + (size_t)2 * C_ * C_, we8, flag);
  conv_mat<<<(we8 + 255) / 256, 256, 0, stream>>>(Wo, Wb + (size_t)3 * C_ * C_, we8, flag);
  conv_bias<<<8, 256, 0, stream>>>(bq, bk, bv, bo, biasf, flag);

  qkv_gemm<<<dim3(C_ / 128, MTOT / 128, 3), 256, 0, stream>>>(xb, Wb, biasf, qkv);
  attn_kernel<<<dim3(T_ / 256, H_, B_), 256, 0, stream>>>(qkv, y);
  out_gemm<<<dim3(C_ / 128, MTOT / 128, 1), 256, 0, stream>>>(
      y, Wb + (size_t)3 * C_ * C_, biasf + 3 * C_, d_out, flag);
}

// Round 4
// 208.691 us; speedup vs baseline: 1.1155x; 1.1155x over previous
//
#include <hip/hip_runtime.h>
#include <hip/hip_bf16.h>

// Problem constants
#define B_    4
#define T_    4096
#define C_    512
#define H_    8
#define D_    64
#define KS_   9
#define PAD_  4
#define MTOT  (B_ * T_)          // 16384
#define PLANE (MTOT * C_)        // 8,388,608 elements per q/k/v plane
#define XU    (MTOT * C_ / 8)    // x units of 8 elements
#define WU    (C_ * C_ / 8)      // weight units of 8 elements

typedef __bf16 bf16_t;
typedef __bf16 bf16x8 __attribute__((ext_vector_type(8)));
typedef float  f32x4  __attribute__((ext_vector_type(4)));

// ---------------------------------------------------------------------------
// Fused fp32 -> bf16 conversion: x (XU units) then Wq,Wk,Wv,Wo (WU each).
// dst: [xb | Wb0 | Wb1 | Wb2 | Wb3] contiguous. 1,179,648 units = 4608 blocks.
// ---------------------------------------------------------------------------
__global__ __launch_bounds__(256)
void conv_all(const float* __restrict__ x,  const float* __restrict__ Wq,
              const float* __restrict__ Wk, const float* __restrict__ Wv,
              const float* __restrict__ Wo, bf16_t* __restrict__ dst) {
  int i = blockIdx.x * 256 + threadIdx.x;
  const float* s;
  if (i < XU) {
    s = x + (size_t)i * 8;
  } else {
    int r = i - XU;
    int w = r >> 15;                       // WU = 1<<15
    const float* W = (w == 0) ? Wq : (w == 1) ? Wk : (w == 2) ? Wv : Wo;
    s = W + (size_t)(r & (WU - 1)) * 8;
  }
  float4 f0 = ((const float4*)s)[0];
  float4 f1 = ((const float4*)s)[1];
  bf16x8 o;
  o[0] = (bf16_t)f0.x; o[1] = (bf16_t)f0.y; o[2] = (bf16_t)f0.z; o[3] = (bf16_t)f0.w;
  o[4] = (bf16_t)f1.x; o[5] = (bf16_t)f1.y; o[6] = (bf16_t)f1.z; o[7] = (bf16_t)f1.w;
  ((bf16x8*)dst)[i] = o;
}

// ---------------------------------------------------------------------------
// GEMM main loop (m97 pattern): C[M,N] = A[M,K] * W[N,K]^T, K = 512, BK = 32,
// 128x128 tile, mfma_f32_16x16x32_bf16, global_load_lds width=16 staging.
// 256 threads = 4 waves 2x2; each wave 4x4 16x16 subtiles (64x64).
// ---------------------------------------------------------------------------
__device__ __forceinline__ void gemm_main(const bf16_t* __restrict__ A,
                                          const bf16_t* __restrict__ W,
                                          int m0, int n0, f32x4 acc[4][4]) {
  constexpr int K = C_;
  __shared__ __align__(16) bf16_t lsA[128 * 32];
  __shared__ __align__(16) bf16_t lsB[128 * 32];

  const int tid  = threadIdx.x;
  const int lane = tid & 63;
  const int wave = tid >> 6;
  const int wm   = (wave >> 1) * 64;
  const int wn   = (wave & 1) * 64;

  for (int k0 = 0; k0 < K; k0 += 32) {
    __syncthreads();   // previous iteration's LDS reads complete
#pragma unroll
    for (int s = 0; s < 2; ++s) {
      // unit u covers 16 B = 8 bf16: row = u/4, kpart = (u%4)*8.
      // LDS dest = wave-uniform base + lane*16  (contract of global_load_lds)
      int u   = s * 256 + tid;
      int row = u >> 2;
      int kp  = (u & 3) << 3;
      const bf16_t* ga = A + ((size_t)(m0 + row) * K + (k0 + kp));
      const bf16_t* gb = W + ((size_t)(n0 + row) * K + (k0 + kp));
      __builtin_amdgcn_global_load_lds(
          (const __attribute__((address_space(1))) unsigned int*)ga,
          (__attribute__((address_space(3))) unsigned int*)&lsA[u * 8], 16, 0, 0);
      __builtin_amdgcn_global_load_lds(
          (const __attribute__((address_space(1))) unsigned int*)gb,
          (__attribute__((address_space(3))) unsigned int*)&lsB[u * 8], 16, 0, 0);
    }
    __syncthreads();   // vmcnt drained before barrier -> staging visible

    const int kq = (lane >> 4) << 3;
    const int rr = lane & 15;
    bf16x8 af[4], bfr[4];
#pragma unroll
    for (int i = 0; i < 4; ++i) {
      af[i]  = *(const bf16x8*)&lsA[(wm + i * 16 + rr) * 32 + kq];
      bfr[i] = *(const bf16x8*)&lsB[(wn + i * 16 + rr) * 32 + kq];
    }
#pragma unroll
    for (int i = 0; i < 4; ++i)
#pragma unroll
      for (int j = 0; j < 4; ++j)
        acc[i][j] = __builtin_amdgcn_mfma_f32_16x16x32_bf16(af[i], bfr[j],
                                                            acc[i][j], 0, 0, 0);
  }
}

// qkv GEMM: writes bf16 per-head planes qkv[z][b][h][t][d].
__global__ __launch_bounds__(256, 2)
void qkv_gemm(const bf16_t* __restrict__ xb, const bf16_t* __restrict__ Wb,
              const float* __restrict__ bq, const float* __restrict__ bk,
              const float* __restrict__ bv, bf16_t* __restrict__ qkv) {
  const int z  = blockIdx.z;
  const int m0 = blockIdx.y * 128, n0 = blockIdx.x * 128;
  f32x4 acc[4][4] = {};
  gemm_main(xb, Wb + (size_t)z * C_ * C_, m0, n0, acc);

  const float* bias = (z == 0) ? bq : (z == 1) ? bk : bv;
  const int tid = threadIdx.x, lane = tid & 63, wave = tid >> 6;
  const int wm = (wave >> 1) * 64, wn = (wave & 1) * 64;
  const int cn = lane & 15, rb = (lane >> 4) << 2;

  // C/D layout: col = lane&15, row = (lane>>4)*4 + reg  [m89]
  float bvals[4];
#pragma unroll
  for (int j = 0; j < 4; ++j) bvals[j] = bias[n0 + wn + j * 16 + cn];

  const int bb = m0 >> 12;              // batch (128-row tile never crosses b)
  const int hh = (n0 + wn) >> 6;        // head (64-col aligned per wave)
  bf16_t* hb = qkv + (size_t)z * PLANE + (size_t)(bb * H_ + hh) * T_ * D_;
#pragma unroll
  for (int i = 0; i < 4; ++i) {
#pragma unroll
    for (int r = 0; r < 4; ++r) {
      int t = (m0 + wm + i * 16 + rb + r) & (T_ - 1);
      bf16_t* row = hb + (size_t)t * D_;
#pragma unroll
      for (int j = 0; j < 4; ++j)
        row[j * 16 + cn] = (bf16_t)(acc[i][j][r] + bvals[j]);
    }
  }
}

// Output GEMM: fp32 row-major [MTOT, C] to d_out.
__global__ __launch_bounds__(256, 2)
void out_gemm(const bf16_t* __restrict__ y, const bf16_t* __restrict__ Wob,
              const float* __restrict__ bo, float* __restrict__ out) {
  const int m0 = blockIdx.y * 128, n0 = blockIdx.x * 128;
  f32x4 acc[4][4] = {};
  gemm_main(y, Wob, m0, n0, acc);

  const int tid = threadIdx.x, lane = tid & 63, wave = tid >> 6;
  const int wm = (wave >> 1) * 64, wn = (wave & 1) * 64;
  const int cn = lane & 15, rb = (lane >> 4) << 2;
  float bvals[4];
#pragma unroll
  for (int j = 0; j < 4; ++j) bvals[j] = bo[n0 + wn + j * 16 + cn];
#pragma unroll
  for (int i = 0; i < 4; ++i) {
#pragma unroll
    for (int r = 0; r < 4; ++r) {
      int gm = m0 + wm + i * 16 + rb + r;
      float* orow = out + (size_t)gm * C_ + (n0 + wn);
#pragma unroll
      for (int j = 0; j < 4; ++j)
        orow[j * 16 + cn] = acc[i][j][r] + bvals[j];
    }
  }
}

// ---------------------------------------------------------------------------
// Neighborhood attention: one thread per (b,h,t). qkv in per-head planes
// (b,h,t,d): lane stride is 128 B -> coalesced 8 KB wave reads, window fits
// L1. y written as (b,t,C) bf16 for the out GEMM. Edge pad = index clamp.
// ---------------------------------------------------------------------------
__global__ __launch_bounds__(256)
void attn_kernel(const bf16_t* __restrict__ qkv, bf16_t* __restrict__ y) {
  const int t = blockIdx.x * 256 + threadIdx.x;
  const int h = blockIdx.y;
  const int b = blockIdx.z;

  const size_t pl = (size_t)(b * H_ + h) * T_ * D_;
  const bf16_t* q = qkv + pl;
  const bf16_t* k = qkv + (size_t)PLANE + pl;
  const bf16_t* v = qkv + (size_t)2 * PLANE + pl;

  int tj[KS_];
#pragma unroll
  for (int j = 0; j < KS_; ++j) {
    int tt = t - PAD_ + j;
    tj[j] = tt < 0 ? 0 : (tt >= T_ ? T_ - 1 : tt);
  }

  float s[KS_];
#pragma unroll
  for (int j = 0; j < KS_; ++j) s[j] = 0.f;

  const bf16_t* qr = q + (size_t)t * D_;
  for (int c = 0; c < D_; c += 8) {
    bf16x8 q8 = *(const bf16x8*)(qr + c);
    float qf[8];
#pragma unroll
    for (int e = 0; e < 8; ++e) qf[e] = (float)q8[e];
#pragma unroll
    for (int j = 0; j < KS_; ++j) {
      bf16x8 k8 = *(const bf16x8*)(k + (size_t)tj[j] * D_ + c);
      float d0 = 0.f;
#pragma unroll
      for (int e = 0; e < 8; ++e) d0 += qf[e] * (float)k8[e];
      s[j] += d0;
    }
  }

  float mx = s[0];
#pragma unroll
  for (int j = 1; j < KS_; ++j) mx = fmaxf(mx, s[j]);
  float w[KS_], sum = 0.f;
#pragma unroll
  for (int j = 0; j < KS_; ++j) {
    w[j] = __expf((s[j] - mx) * 0.125f);   // scale = 1/sqrt(64)
    sum += w[j];
  }
  const float inv = 1.f / sum;
#pragma unroll
  for (int j = 0; j < KS_; ++j) w[j] *= inv;

  bf16_t* yr = y + (size_t)(b * T_ + t) * C_ + h * D_;
  for (int c = 0; c < D_; c += 8) {
    float o[8] = {0.f, 0.f, 0.f, 0.f, 0.f, 0.f, 0.f, 0.f};
#pragma unroll
    for (int j = 0; j < KS_; ++j) {
      bf16x8 v8 = *(const bf16x8*)(v + (size_t)tj[j] * D_ + c);
#pragma unroll
      for (int e = 0; e < 8; ++e) o[e] += w[j] * (float)v8[e];
    }
    bf16x8 o8;
#pragma unroll
    for (int e = 0; e < 8; ++e) o8[e] = (bf16_t)o[e];
    *(bf16x8*)(yr + c) = o8;
  }
}

// ---------------------------------------------------------------------------
extern "C" void kernel_launch(void* const* d_in, const int* in_sizes, int n_in,
                              void* d_out, int out_size, void* d_ws, size_t ws_size,
                              hipStream_t stream) {
  const float* x  = (const float*)d_in[0];
  const float* Wq = (const float*)d_in[1];
  const float* bq = (const float*)d_in[2];
  const float* Wk = (const float*)d_in[3];
  const float* bk = (const float*)d_in[4];
  const float* Wv = (const float*)d_in[5];
  const float* bv = (const float*)d_in[6];
  const float* Wo = (const float*)d_in[7];
  const float* bo = (const float*)d_in[8];
  float* out = (float*)d_out;

  // Workspace: xb 16MB | Wb 2MB | qkv 48MB | y 16MB  = 82 MB
  bf16_t* xb  = (bf16_t*)d_ws;
  bf16_t* Wb  = xb + (size_t)MTOT * C_;
  bf16_t* qkv = Wb + (size_t)4 * C_ * C_;
  bf16_t* y   = qkv + (size_t)3 * PLANE;

  conv_all<<<(XU + 4 * WU) / 256, 256, 0, stream>>>(x, Wq, Wk, Wv, Wo, xb);
  qkv_gemm<<<dim3(C_ / 128, MTOT / 128, 3), 256, 0, stream>>>(
      xb, Wb, bq, bk, bv, qkv);
  attn_kernel<<<dim3(T_ / 256, H_, B_), 256, 0, stream>>>(qkv, y);
  out_gemm<<<dim3(C_ / 128, MTOT / 128, 1), 256, 0, stream>>>(y, Wb + (size_t)3 * C_ * C_, bo, out);
}

// Round 5
// 176.155 us; speedup vs baseline: 1.3215x; 1.1847x over previous
//
#include <hip/hip_runtime.h>
#include <hip/hip_bf16.h>

// Problem constants
#define B_    4
#define T_    4096
#define C_    512
#define H_    8
#define D_    64
#define KS_   9
#define PAD_  4
#define MTOT  (B_ * T_)          // 16384
#define PLANE (MTOT * C_)        // 8,388,608 elements per q/k/v plane
#define XU    (MTOT * C_ / 8)    // x units of 8 elements
#define WU    (C_ * C_ / 8)      // weight units of 8 elements

typedef __bf16 bf16_t;
typedef __bf16 bf16x8 __attribute__((ext_vector_type(8)));
typedef float  f32x4  __attribute__((ext_vector_type(4)));

// ---------------------------------------------------------------------------
// Fused fp32 -> bf16 conversion: x (XU units) then Wq,Wk,Wv,Wo (WU each).
// ---------------------------------------------------------------------------
__global__ __launch_bounds__(256)
void conv_all(const float* __restrict__ x,  const float* __restrict__ Wq,
              const float* __restrict__ Wk, const float* __restrict__ Wv,
              const float* __restrict__ Wo, bf16_t* __restrict__ dst) {
  int i = blockIdx.x * 256 + threadIdx.x;
  const float* s;
  if (i < XU) {
    s = x + (size_t)i * 8;
  } else {
    int r = i - XU;
    int w = r >> 15;                       // WU = 1<<15
    const float* W = (w == 0) ? Wq : (w == 1) ? Wk : (w == 2) ? Wv : Wo;
    s = W + (size_t)(r & (WU - 1)) * 8;
  }
  float4 f0 = ((const float4*)s)[0];
  float4 f1 = ((const float4*)s)[1];
  bf16x8 o;
  o[0] = (bf16_t)f0.x; o[1] = (bf16_t)f0.y; o[2] = (bf16_t)f0.z; o[3] = (bf16_t)f0.w;
  o[4] = (bf16_t)f1.x; o[5] = (bf16_t)f1.y; o[6] = (bf16_t)f1.z; o[7] = (bf16_t)f1.w;
  ((bf16x8*)dst)[i] = o;
}

// ---------------------------------------------------------------------------
// GEMM main loop (m97 pattern): C[M,N] = A[M,K] * W[N,K]^T, K = 512, BK = 32,
// 128x128 tile, mfma_f32_16x16x32_bf16, global_load_lds width=16 staging.
// APLANE: A is stored as per-head planes (b,h,t,d) instead of row-major
// [M, K]. Each BK=32 slab lies within one head (32 | 64), so h = k0>>6.
// ---------------------------------------------------------------------------
template <bool APLANE>
__device__ __forceinline__ void gemm_main(const bf16_t* __restrict__ A,
                                          const bf16_t* __restrict__ W,
                                          int m0, int n0, f32x4 acc[4][4]) {
  constexpr int K = C_;
  __shared__ __align__(16) bf16_t lsA[128 * 32];
  __shared__ __align__(16) bf16_t lsB[128 * 32];

  const int tid  = threadIdx.x;
  const int lane = tid & 63;
  const int wave = tid >> 6;
  const int wm   = (wave >> 1) * 64;
  const int wn   = (wave & 1) * 64;

  for (int k0 = 0; k0 < K; k0 += 32) {
    __syncthreads();   // previous iteration's LDS reads complete
#pragma unroll
    for (int s = 0; s < 2; ++s) {
      // unit u covers 16 B = 8 bf16: row = u/4, kpart = (u%4)*8.
      int u   = s * 256 + tid;
      int row = u >> 2;
      int kp  = (u & 3) << 3;
      const bf16_t* ga;
      if (APLANE) {
        int m = m0 + row;
        int b = m >> 12, t = m & (T_ - 1);
        int h = k0 >> 6, d0 = (k0 & 63) + kp;
        ga = A + (((size_t)(b * H_ + h) * T_ + t) * D_ + d0);
      } else {
        ga = A + ((size_t)(m0 + row) * K + (k0 + kp));
      }
      const bf16_t* gb = W + ((size_t)(n0 + row) * K + (k0 + kp));
      __builtin_amdgcn_global_load_lds(
          (const __attribute__((address_space(1))) unsigned int*)ga,
          (__attribute__((address_space(3))) unsigned int*)&lsA[u * 8], 16, 0, 0);
      __builtin_amdgcn_global_load_lds(
          (const __attribute__((address_space(1))) unsigned int*)gb,
          (__attribute__((address_space(3))) unsigned int*)&lsB[u * 8], 16, 0, 0);
    }
    __syncthreads();   // vmcnt drained before barrier -> staging visible

    const int kq = (lane >> 4) << 3;
    const int rr = lane & 15;
    bf16x8 af[4], bfr[4];
#pragma unroll
    for (int i = 0; i < 4; ++i) {
      af[i]  = *(const bf16x8*)&lsA[(wm + i * 16 + rr) * 32 + kq];
      bfr[i] = *(const bf16x8*)&lsB[(wn + i * 16 + rr) * 32 + kq];
    }
#pragma unroll
    for (int i = 0; i < 4; ++i)
#pragma unroll
      for (int j = 0; j < 4; ++j)
        acc[i][j] = __builtin_amdgcn_mfma_f32_16x16x32_bf16(af[i], bfr[j],
                                                            acc[i][j], 0, 0, 0);
  }
}

// qkv GEMM: writes bf16 per-head planes qkv[z][b][h][t][d].
__global__ __launch_bounds__(256, 2)
void qkv_gemm(const bf16_t* __restrict__ xb, const bf16_t* __restrict__ Wb,
              const float* __restrict__ bq, const float* __restrict__ bk,
              const float* __restrict__ bv, bf16_t* __restrict__ qkv) {
  const int z  = blockIdx.z;
  const int m0 = blockIdx.y * 128, n0 = blockIdx.x * 128;
  f32x4 acc[4][4] = {};
  gemm_main<false>(xb, Wb + (size_t)z * C_ * C_, m0, n0, acc);

  const float* bias = (z == 0) ? bq : (z == 1) ? bk : bv;
  const int tid = threadIdx.x, lane = tid & 63, wave = tid >> 6;
  const int wm = (wave >> 1) * 64, wn = (wave & 1) * 64;
  const int cn = lane & 15, rb = (lane >> 4) << 2;

  // C/D layout: col = lane&15, row = (lane>>4)*4 + reg  [m89]
  float bvals[4];
#pragma unroll
  for (int j = 0; j < 4; ++j) bvals[j] = bias[n0 + wn + j * 16 + cn];

  const int bb = m0 >> 12;              // batch (128-row tile never crosses b)
  const int hh = (n0 + wn) >> 6;        // head (64-col aligned per wave)
  bf16_t* hb = qkv + (size_t)z * PLANE + (size_t)(bb * H_ + hh) * T_ * D_;
#pragma unroll
  for (int i = 0; i < 4; ++i) {
#pragma unroll
    for (int r = 0; r < 4; ++r) {
      int t = (m0 + wm + i * 16 + rb + r) & (T_ - 1);
      bf16_t* row = hb + (size_t)t * D_;
#pragma unroll
      for (int j = 0; j < 4; ++j)
        row[j * 16 + cn] = (bf16_t)(acc[i][j][r] + bvals[j]);
    }
  }
}

// Output GEMM: A = y in per-head planes; fp32 row-major [MTOT, C] out.
__global__ __launch_bounds__(256, 2)
void out_gemm(const bf16_t* __restrict__ y, const bf16_t* __restrict__ Wob,
              const float* __restrict__ bo, float* __restrict__ out) {
  const int m0 = blockIdx.y * 128, n0 = blockIdx.x * 128;
  f32x4 acc[4][4] = {};
  gemm_main<true>(y, Wob, m0, n0, acc);

  const int tid = threadIdx.x, lane = tid & 63, wave = tid >> 6;
  const int wm = (wave >> 1) * 64, wn = (wave & 1) * 64;
  const int cn = lane & 15, rb = (lane >> 4) << 2;
  float bvals[4];
#pragma unroll
  for (int j = 0; j < 4; ++j) bvals[j] = bo[n0 + wn + j * 16 + cn];
#pragma unroll
  for (int i = 0; i < 4; ++i) {
#pragma unroll
    for (int r = 0; r < 4; ++r) {
      int gm = m0 + wm + i * 16 + rb + r;
      float* orow = out + (size_t)gm * C_ + (n0 + wn);
#pragma unroll
      for (int j = 0; j < 4; ++j)
        orow[j * 16 + cn] = acc[i][j][r] + bvals[j];
    }
  }
}

// ---------------------------------------------------------------------------
// Neighborhood attention: 8 threads per (b,h,t) — thread sub-index handles
// one d-octet (16 B). Scores reduced across the 8 lanes via __shfl_xor
// (width 8). 8x the waves of the 1-thread/t version (64 waves/CU).
// y written to per-head planes (b,h,t,d): wave stores 1024 B contiguous.
// ---------------------------------------------------------------------------
__global__ __launch_bounds__(256)
void attn_kernel(const bf16_t* __restrict__ qkv, bf16_t* __restrict__ y) {
  const int tid  = threadIdx.x;
  const int sub  = tid & 7;              // d-octet index
  const int tl   = tid >> 3;             // 0..31 t's per block
  const int t    = blockIdx.x * 32 + tl;
  const int h    = blockIdx.y;
  const int b    = blockIdx.z;

  const size_t pl = (size_t)(b * H_ + h) * T_ * D_;
  const bf16_t* q = qkv + pl;
  const bf16_t* k = qkv + (size_t)PLANE + pl;
  const bf16_t* v = qkv + (size_t)2 * PLANE + pl;
  const int c = sub * 8;

  int tj[KS_];
#pragma unroll
  for (int j = 0; j < KS_; ++j) {
    int tt = t - PAD_ + j;
    tj[j] = tt < 0 ? 0 : (tt >= T_ ? T_ - 1 : tt);
  }

  // Load this thread's q-octet and the 9 k-octets; partial dot products.
  bf16x8 q8 = *(const bf16x8*)(q + (size_t)t * D_ + c);
  float qf[8];
#pragma unroll
  for (int e = 0; e < 8; ++e) qf[e] = (float)q8[e];

  float s[KS_];
#pragma unroll
  for (int j = 0; j < KS_; ++j) {
    bf16x8 k8 = *(const bf16x8*)(k + (size_t)tj[j] * D_ + c);
    float d0 = 0.f;
#pragma unroll
    for (int e = 0; e < 8; ++e) d0 += qf[e] * (float)k8[e];
    s[j] = d0;
  }

  // Cross-lane reduce over the 8 sub-lanes (butterfly, width 8).
#pragma unroll
  for (int m = 1; m < 8; m <<= 1)
#pragma unroll
    for (int j = 0; j < KS_; ++j) s[j] += __shfl_xor(s[j], m, 8);

  // Softmax (replicated in all 8 lanes — cheap).
  float mx = s[0];
#pragma unroll
  for (int j = 1; j < KS_; ++j) mx = fmaxf(mx, s[j]);
  float w[KS_], sum = 0.f;
#pragma unroll
  for (int j = 0; j < KS_; ++j) {
    w[j] = __expf((s[j] - mx) * 0.125f);   // scale = 1/sqrt(64)
    sum += w[j];
  }
  const float inv = 1.f / sum;
#pragma unroll
  for (int j = 0; j < KS_; ++j) w[j] *= inv;

  // PV: this thread's d-octet across the 9 neighbors.
  float o[8] = {0.f, 0.f, 0.f, 0.f, 0.f, 0.f, 0.f, 0.f};
#pragma unroll
  for (int j = 0; j < KS_; ++j) {
    bf16x8 v8 = *(const bf16x8*)(v + (size_t)tj[j] * D_ + c);
#pragma unroll
    for (int e = 0; e < 8; ++e) o[e] += w[j] * (float)v8[e];
  }
  bf16x8 o8;
#pragma unroll
  for (int e = 0; e < 8; ++e) o8[e] = (bf16_t)o[e];
  *(bf16x8*)(y + pl + (size_t)t * D_ + c) = o8;   // wave: 1024 B contiguous
}

// ---------------------------------------------------------------------------
extern "C" void kernel_launch(void* const* d_in, const int* in_sizes, int n_in,
                              void* d_out, int out_size, void* d_ws, size_t ws_size,
                              hipStream_t stream) {
  const float* x  = (const float*)d_in[0];
  const float* Wq = (const float*)d_in[1];
  const float* bq = (const float*)d_in[2];
  const float* Wk = (const float*)d_in[3];
  const float* bk = (const float*)d_in[4];
  const float* Wv = (const float*)d_in[5];
  const float* bv = (const float*)d_in[6];
  const float* Wo = (const float*)d_in[7];
  const float* bo = (const float*)d_in[8];
  float* out = (float*)d_out;

  // Workspace: xb 16MB | Wb 2MB | qkv 48MB | y 16MB  = 82 MB
  bf16_t* xb  = (bf16_t*)d_ws;
  bf16_t* Wb  = xb + (size_t)MTOT * C_;
  bf16_t* qkv = Wb + (size_t)4 * C_ * C_;
  bf16_t* y   = qkv + (size_t)3 * PLANE;

  conv_all<<<(XU + 4 * WU) / 256, 256, 0, stream>>>(x, Wq, Wk, Wv, Wo, xb);
  qkv_gemm<<<dim3(C_ / 128, MTOT / 128, 3), 256, 0, stream>>>(
      xb, Wb, bq, bk, bv, qkv);
  attn_kernel<<<dim3(T_ / 32, H_, B_), 256, 0, stream>>>(qkv, y);
  out_gemm<<<dim3(C_ / 128, MTOT / 128, 1), 256, 0, stream>>>(
      y, Wb + (size_t)3 * C_ * C_, bo, out);
}

// Round 6
// 169.280 us; speedup vs baseline: 1.3752x; 1.0406x over previous
//
#include <hip/hip_runtime.h>
#include <hip/hip_bf16.h>

// Problem constants
#define B_    4
#define T_    4096
#define C_    512
#define H_    8
#define D_    64
#define KS_   9
#define PAD_  4
#define MTOT  (B_ * T_)          // 16384
#define PLANE (MTOT * C_)        // elements per q/k/v plane
#define WU    (C_ * C_ / 8)      // weight units of 8 elements

typedef __bf16 bf16_t;
typedef __bf16 bf16x8 __attribute__((ext_vector_type(8)));
typedef float  f32x4  __attribute__((ext_vector_type(4)));

// ---------------------------------------------------------------------------
// Weights fp32 -> bf16 (x is consumed as fp32 directly by qkv_gemm now).
// ---------------------------------------------------------------------------
__global__ __launch_bounds__(256)
void conv_w(const float* __restrict__ Wq, const float* __restrict__ Wk,
            const float* __restrict__ Wv, const float* __restrict__ Wo,
            bf16_t* __restrict__ dst) {
  int i = blockIdx.x * 256 + threadIdx.x;       // 0 .. 4*WU-1
  int w = i >> 15;                              // WU = 1<<15
  const float* W = (w == 0) ? Wq : (w == 1) ? Wk : (w == 2) ? Wv : Wo;
  const float* s = W + (size_t)(i & (WU - 1)) * 8;
  float4 f0 = ((const float4*)s)[0];
  float4 f1 = ((const float4*)s)[1];
  bf16x8 o;
  o[0] = (bf16_t)f0.x; o[1] = (bf16_t)f0.y; o[2] = (bf16_t)f0.z; o[3] = (bf16_t)f0.w;
  o[4] = (bf16_t)f1.x; o[5] = (bf16_t)f1.y; o[6] = (bf16_t)f1.z; o[7] = (bf16_t)f1.w;
  ((bf16x8*)dst)[i] = o;
}

// ---------------------------------------------------------------------------
// qkv GEMM, z-merged: one block computes the 128(t) x 128(col) tile of
// q, k AND v. A (x, fp32) is staged once per k-iter (register convert to
// bf16 + ds_write); B slabs for all 3 weights staged via global_load_lds.
// XOR chunk swizzle kills the 8-way bank conflict of the 64-B-row layout:
// LDS slot s of row r holds global k-chunk s ^ ((r>>1)&3).
// acc[3][4][4] f32x4 = 192 VGPR; launch_bounds(256,2) caps at 256.
// ---------------------------------------------------------------------------
__global__ __launch_bounds__(256, 2)
void qkv_gemm(const float* __restrict__ x, const bf16_t* __restrict__ Wb,
              const float* __restrict__ bq, const float* __restrict__ bk,
              const float* __restrict__ bv, bf16_t* __restrict__ qkv) {
  __shared__ __align__(16) bf16_t lsA[128 * 32];
  __shared__ __align__(16) bf16_t lsB[3][128 * 32];

  const int tid  = threadIdx.x;
  const int lane = tid & 63;
  const int wave = tid >> 6;
  const int wm   = (wave >> 1) * 64;
  const int wn   = (wave & 1) * 64;
  const int m0   = blockIdx.y * 128;
  const int n0   = blockIdx.x * 128;

  f32x4 acc[3][4][4] = {};

  for (int k0 = 0; k0 < C_; k0 += 32) {
    // A: fp32 -> bf16 register staging with chunk swizzle (2 units/thread)
    bf16x8 a[2];
#pragma unroll
    for (int s = 0; s < 2; ++s) {
      int u = s * 256 + tid;
      int row = u >> 2, slot = u & 3;
      int c = slot ^ ((row >> 1) & 3);
      const float* src = x + (size_t)(m0 + row) * C_ + k0 + c * 8;
      float4 f0 = ((const float4*)src)[0];
      float4 f1 = ((const float4*)src)[1];
      a[s][0] = (bf16_t)f0.x; a[s][1] = (bf16_t)f0.y;
      a[s][2] = (bf16_t)f0.z; a[s][3] = (bf16_t)f0.w;
      a[s][4] = (bf16_t)f1.x; a[s][5] = (bf16_t)f1.y;
      a[s][6] = (bf16_t)f1.z; a[s][7] = (bf16_t)f1.w;
    }

    __syncthreads();   // previous iteration's LDS reads complete
    *(bf16x8*)&lsA[(size_t)tid * 8]         = a[0];
    *(bf16x8*)&lsA[(size_t)(tid + 256) * 8] = a[1];
#pragma unroll
    for (int z = 0; z < 3; ++z)
#pragma unroll
      for (int s = 0; s < 2; ++s) {
        int u = s * 256 + tid;
        int row = u >> 2, slot = u & 3;
        int c = slot ^ ((row >> 1) & 3);
        const bf16_t* gb = Wb + (size_t)z * C_ * C_ +
                           (size_t)(n0 + row) * C_ + k0 + c * 8;
        __builtin_amdgcn_global_load_lds(
            (const __attribute__((address_space(1))) unsigned int*)gb,
            (__attribute__((address_space(3))) unsigned int*)&lsB[z][u * 8],
            16, 0, 0);
      }
    __syncthreads();   // vmcnt+lgkmcnt drained -> staging visible

    const int rr = lane & 15;
    const int q  = lane >> 4;
    const int sl = (q ^ ((rr >> 1) & 3)) << 3;   // swizzled slot, in elements
    bf16x8 af[4];
#pragma unroll
    for (int i = 0; i < 4; ++i)
      af[i] = *(const bf16x8*)&lsA[(wm + i * 16 + rr) * 32 + sl];
#pragma unroll
    for (int z = 0; z < 3; ++z) {
      bf16x8 bfr[4];
#pragma unroll
      for (int j = 0; j < 4; ++j)
        bfr[j] = *(const bf16x8*)&lsB[z][(wn + j * 16 + rr) * 32 + sl];
#pragma unroll
      for (int i = 0; i < 4; ++i)
#pragma unroll
        for (int j = 0; j < 4; ++j)
          acc[z][i][j] = __builtin_amdgcn_mfma_f32_16x16x32_bf16(
              af[i], bfr[j], acc[z][i][j], 0, 0, 0);
    }
  }

  // Epilogue: C/D layout col = lane&15, row = (lane>>4)*4 + reg  [m89]
  const int cn = lane & 15;
  const int rb = (lane >> 4) << 2;
  const int bb = m0 >> 12;              // batch (tile never crosses b)
  const int hh = (n0 + wn) >> 6;        // head (64-col aligned per wave)
#pragma unroll
  for (int z = 0; z < 3; ++z) {
    const float* bias = (z == 0) ? bq : (z == 1) ? bk : bv;
    float bvals[4];
#pragma unroll
    for (int j = 0; j < 4; ++j) bvals[j] = bias[n0 + wn + j * 16 + cn];
    bf16_t* hb = qkv + (size_t)z * PLANE + (size_t)(bb * H_ + hh) * T_ * D_;
#pragma unroll
    for (int i = 0; i < 4; ++i) {
#pragma unroll
      for (int r = 0; r < 4; ++r) {
        int t = (m0 + wm + i * 16 + rb + r) & (T_ - 1);
        bf16_t* row = hb + (size_t)t * D_;
#pragma unroll
        for (int j = 0; j < 4; ++j)
          row[j * 16 + cn] = (bf16_t)(acc[z][i][j][r] + bvals[j]);
      }
    }
  }
}

// ---------------------------------------------------------------------------
// Output GEMM: A = y in per-head planes (b,h,t,d); fp32 [MTOT, C] out.
// Same XOR chunk swizzle. BK=32 slab lies within one head (32 | 64).
// ---------------------------------------------------------------------------
__global__ __launch_bounds__(256, 2)
void out_gemm(const bf16_t* __restrict__ y, const bf16_t* __restrict__ Wob,
              const float* __restrict__ bo, float* __restrict__ out) {
  __shared__ __align__(16) bf16_t lsA[128 * 32];
  __shared__ __align__(16) bf16_t lsB[128 * 32];

  const int tid  = threadIdx.x;
  const int lane = tid & 63;
  const int wave = tid >> 6;
  const int wm   = (wave >> 1) * 64;
  const int wn   = (wave & 1) * 64;
  const int m0   = blockIdx.y * 128;
  const int n0   = blockIdx.x * 128;

  f32x4 acc[4][4] = {};

  for (int k0 = 0; k0 < C_; k0 += 32) {
    __syncthreads();
#pragma unroll
    for (int s = 0; s < 2; ++s) {
      int u = s * 256 + tid;
      int row = u >> 2, slot = u & 3;
      int c = slot ^ ((row >> 1) & 3);
      int m = m0 + row;
      int b = m >> 12, t = m & (T_ - 1);
      int h = k0 >> 6, d0 = (k0 & 63) + c * 8;
      const bf16_t* ga = y + (((size_t)(b * H_ + h) * T_ + t) * D_ + d0);
      const bf16_t* gb = Wob + (size_t)(n0 + row) * C_ + k0 + c * 8;
      __builtin_amdgcn_global_load_lds(
          (const __attribute__((address_space(1))) unsigned int*)ga,
          (__attribute__((address_space(3))) unsigned int*)&lsA[u * 8], 16, 0, 0);
      __builtin_amdgcn_global_load_lds(
          (const __attribute__((address_space(1))) unsigned int*)gb,
          (__attribute__((address_space(3))) unsigned int*)&lsB[u * 8], 16, 0, 0);
    }
    __syncthreads();

    const int rr = lane & 15;
    const int q  = lane >> 4;
    const int sl = (q ^ ((rr >> 1) & 3)) << 3;
    bf16x8 af[4], bfr[4];
#pragma unroll
    for (int i = 0; i < 4; ++i) {
      af[i]  = *(const bf16x8*)&lsA[(wm + i * 16 + rr) * 32 + sl];
      bfr[i] = *(const bf16x8*)&lsB[(wn + i * 16 + rr) * 32 + sl];
    }
#pragma unroll
    for (int i = 0; i < 4; ++i)
#pragma unroll
      for (int j = 0; j < 4; ++j)
        acc[i][j] = __builtin_amdgcn_mfma_f32_16x16x32_bf16(af[i], bfr[j],
                                                            acc[i][j], 0, 0, 0);
  }

  const int cn = lane & 15;
  const int rb = (lane >> 4) << 2;
  float bvals[4];
#pragma unroll
  for (int j = 0; j < 4; ++j) bvals[j] = bo[n0 + wn + j * 16 + cn];
#pragma unroll
  for (int i = 0; i < 4; ++i) {
#pragma unroll
    for (int r = 0; r < 4; ++r) {
      int gm = m0 + wm + i * 16 + rb + r;
      float* orow = out + (size_t)gm * C_ + (n0 + wn);
#pragma unroll
      for (int j = 0; j < 4; ++j)
        orow[j * 16 + cn] = acc[i][j][r] + bvals[j];
    }
  }
}

// ---------------------------------------------------------------------------
// Neighborhood attention: 8 threads per (b,h,t), d-octet each; width-8
// shfl_xor score reduce; per-head plane I/O (fully coalesced).
// ---------------------------------------------------------------------------
__global__ __launch_bounds__(256)
void attn_kernel(const bf16_t* __restrict__ qkv, bf16_t* __restrict__ y) {
  const int tid  = threadIdx.x;
  const int sub  = tid & 7;
  const int tl   = tid >> 3;
  const int t    = blockIdx.x * 32 + tl;
  const int h    = blockIdx.y;
  const int b    = blockIdx.z;

  const size_t pl = (size_t)(b * H_ + h) * T_ * D_;
  const bf16_t* q = qkv + pl;
  const bf16_t* k = qkv + (size_t)PLANE + pl;
  const bf16_t* v = qkv + (size_t)2 * PLANE + pl;
  const int c = sub * 8;

  int tj[KS_];
#pragma unroll
  for (int j = 0; j < KS_; ++j) {
    int tt = t - PAD_ + j;
    tj[j] = tt < 0 ? 0 : (tt >= T_ ? T_ - 1 : tt);
  }

  bf16x8 q8 = *(const bf16x8*)(q + (size_t)t * D_ + c);
  float qf[8];
#pragma unroll
  for (int e = 0; e < 8; ++e) qf[e] = (float)q8[e];

  float s[KS_];
#pragma unroll
  for (int j = 0; j < KS_; ++j) {
    bf16x8 k8 = *(const bf16x8*)(k + (size_t)tj[j] * D_ + c);
    float d0 = 0.f;
#pragma unroll
    for (int e = 0; e < 8; ++e) d0 += qf[e] * (float)k8[e];
    s[j] = d0;
  }

#pragma unroll
  for (int m = 1; m < 8; m <<= 1)
#pragma unroll
    for (int j = 0; j < KS_; ++j) s[j] += __shfl_xor(s[j], m, 8);

  float mx = s[0];
#pragma unroll
  for (int j = 1; j < KS_; ++j) mx = fmaxf(mx, s[j]);
  float w[KS_], sum = 0.f;
#pragma unroll
  for (int j = 0; j < KS_; ++j) {
    w[j] = __expf((s[j] - mx) * 0.125f);   // scale = 1/sqrt(64)
    sum += w[j];
  }
  const float inv = 1.f / sum;
#pragma unroll
  for (int j = 0; j < KS_; ++j) w[j] *= inv;

  float o[8] = {0.f, 0.f, 0.f, 0.f, 0.f, 0.f, 0.f, 0.f};
#pragma unroll
  for (int j = 0; j < KS_; ++j) {
    bf16x8 v8 = *(const bf16x8*)(v + (size_t)tj[j] * D_ + c);
#pragma unroll
    for (int e = 0; e < 8; ++e) o[e] += w[j] * (float)v8[e];
  }
  bf16x8 o8;
#pragma unroll
  for (int e = 0; e < 8; ++e) o8[e] = (bf16_t)o[e];
  *(bf16x8*)(y + pl + (size_t)t * D_ + c) = o8;
}

// ---------------------------------------------------------------------------
extern "C" void kernel_launch(void* const* d_in, const int* in_sizes, int n_in,
                              void* d_out, int out_size, void* d_ws, size_t ws_size,
                              hipStream_t stream) {
  const float* x  = (const float*)d_in[0];
  const float* Wq = (const float*)d_in[1];
  const float* bq = (const float*)d_in[2];
  const float* Wk = (const float*)d_in[3];
  const float* bk = (const float*)d_in[4];
  const float* Wv = (const float*)d_in[5];
  const float* bv = (const float*)d_in[6];
  const float* Wo = (const float*)d_in[7];
  const float* bo = (const float*)d_in[8];
  float* out = (float*)d_out;

  // Workspace: Wb 2MB | qkv 48MB | y 16MB  = 66 MB
  bf16_t* Wb  = (bf16_t*)d_ws;
  bf16_t* qkv = Wb + (size_t)4 * C_ * C_;
  bf16_t* y   = qkv + (size_t)3 * PLANE;

  conv_w<<<4 * WU / 256, 256, 0, stream>>>(Wq, Wk, Wv, Wo, Wb);
  qkv_gemm<<<dim3(C_ / 128, MTOT / 128), 256, 0, stream>>>(
      x, Wb, bq, bk, bv, qkv);
  attn_kernel<<<dim3(T_ / 32, H_, B_), 256, 0, stream>>>(qkv, y);
  out_gemm<<<dim3(C_ / 128, MTOT / 128, 1), 256, 0, stream>>>(
      y, Wb + (size_t)3 * C_ * C_, bo, out);
}